// Round 8
// baseline (69.587 us; speedup 1.0000x reference)
//
#include <hip/hip_runtime.h>
#include <stdint.h>

#define NREG   20
#define EDIM   768
#define DVOL   64
#define HVOL   512
#define WVOL   512
#define HW_    (HVOL * WVOL)
#define DHW_   (DVOL * HVOL * WVOL)
#define NPATCH 16384
#define BTOT   2
#define PROTO_N (NREG * EDIM)            // 15360
#define RF_N    (BTOT * PROTO_N)         // 30720 floats (output 0)
#define TOTAL_PATCHES (BTOT * NPATCH)    // 32768
#define CHUNK   4096                     // patches per sort chunk (8 chunks)

// ---- workspace layout ------------------------------------------------------
// bytes [0, 33.5MB): int8 compact mask (+64B slack for row-overrun reads)
// then u32 words for the sort output.
#define SEG8_BYTES   (BTOT * DHW_)                 // 33,554,432
#define WS_SORT_W    ((SEG8_BYTES + 1024) / 4)     // word offset after slack
#define WS_PID       (WS_SORT_W)
#define WS_C0        (WS_PID + TOTAL_PATCHES)
#define WS_C1        (WS_C0  + TOTAL_PATCHES)
#define WS_C2        (WS_C1  + TOTAL_PATCHES)

#define CMP_BLOCKS   4096
#define CMP_THREADS  256
#define CMP_TOTAL_DW (BTOT * DHW_ / 4)             // 8,388,608 dwords out

// ---------------------------------------------------------------------------
// Pass 1: fully-coalesced int32 -> int8 mask compaction (+ proto broadcast).
// Each thread packs 4 ints -> 1 dword, 8 grid-stride iterations.
// ---------------------------------------------------------------------------
__global__ __launch_bounds__(CMP_THREADS) void compact_kernel(
    const int*   __restrict__ seg,
    const float* __restrict__ proto,
    uint32_t*    __restrict__ seg8w,
    float*       __restrict__ out)
{
    const int tid = (int)blockIdx.x * CMP_THREADS + (int)threadIdx.x;

    if (tid < RF_N) out[tid] = proto[tid >= PROTO_N ? tid - PROTO_N : tid];

#pragma unroll
    for (int it = 0; it < 8; ++it) {
        const int d = tid + it * (CMP_BLOCKS * CMP_THREADS);
        const int4 v = *(const int4*)(seg + 4 * d);
        seg8w[d] = (uint32_t)v.x | ((uint32_t)v.y << 8)
                 | ((uint32_t)v.z << 16) | ((uint32_t)v.w << 24);
    }
}

// ---------------------------------------------------------------------------
// Counting sort (from R6): 8 blocks, each sorts its 4096-patch chunk by
// spatial key (z/2 -> 32 bins, y/32 -> 16 bins) into ws (pid + SoA coords).
// ---------------------------------------------------------------------------
__global__ __launch_bounds__(1024) void sort_kernel(
    const float* __restrict__ coords, unsigned* __restrict__ ws)
{
    __shared__ unsigned counts[512], offs[512];
    const int t  = threadIdx.x;
    const int p0 = (int)blockIdx.x * CHUNK + t * 4;

    if (t < 512) counts[t] = 0u;
    __syncthreads();

    float c[12];
    {
        const float4* cp = (const float4*)(coords + p0 * 3);
        const float4 a = cp[0], b = cp[1], d = cp[2];
        c[0]=a.x; c[1]=a.y; c[2]=a.z;  c[3]=a.w; c[4]=b.x; c[5]=b.y;
        c[6]=b.z; c[7]=b.w; c[8]=d.x;  c[9]=d.y; c[10]=d.z; c[11]=d.w;
    }
    unsigned key[4];
#pragma unroll
    for (int i = 0; i < 4; ++i) {
        const int zb = ((int)(c[3*i + 0] * 64.0f))  >> 1;   // 0..31
        const int yb = ((int)(c[3*i + 1] * 512.0f)) >> 5;   // 0..15
        key[i] = (unsigned)(zb * 16 + yb);
        atomicAdd(&counts[key[i]], 1u);
    }
    __syncthreads();

    if (t < 512) offs[t] = counts[t];
    __syncthreads();
#pragma unroll
    for (int off = 1; off < 512; off <<= 1) {
        const unsigned v = (t >= off && t < 512) ? offs[t - off] : 0u;
        __syncthreads();
        if (t < 512) offs[t] += v;
        __syncthreads();
    }
    if (t < 512) offs[t] -= counts[t];        // exclusive prefix
    __syncthreads();

#pragma unroll
    for (int i = 0; i < 4; ++i) {
        const unsigned rank = (unsigned)blockIdx.x * CHUNK
                            + atomicAdd(&offs[key[i]], 1u);
        ws[WS_PID + rank] = (unsigned)(p0 + i);
        ((float*)ws)[WS_C0 + rank] = c[3*i + 0];
        ((float*)ws)[WS_C1 + rank] = c[3*i + 1];
        ((float*)ws)[WS_C2 + rank] = c[3*i + 2];
    }
}

// ---------------------------------------------------------------------------
// Pass 2: one wave per sorted patch, reading the L3-resident int8 mask.
// Lane = (z = lane>>4, y = lane&15); each lane loads 24B (dwordx4+dwordx2)
// covering its row's 16-byte x-window at any alignment; funnel-shift +
// byte masks; packed 8-bit histogram; shfl butterfly reduce.
// ---------------------------------------------------------------------------
__global__ __launch_bounds__(256) void assign_kernel(
    const uint8_t*  __restrict__ seg8,
    const unsigned* __restrict__ ws,
    float*          __restrict__ out)
{
    // XCD-chunked swizzle: block bid -> sorted chunk (bid & 7)
    const int bid  = (int)blockIdx.x;
    const int sbid = (bid & 7) * 1024 + (bid >> 3);

    const int lane = threadIdx.x & 63;
    const int wave = threadIdx.x >> 6;
    const int slot = sbid * 4 + wave;

    const int   patch = (int)ws[WS_PID + slot];                  // uniform
    const float c0 = ((const float*)ws)[WS_C0 + slot] * 64.0f;   // z
    const float c1 = ((const float*)ws)[WS_C1 + slot] * 512.0f;  // y
    const float c2 = ((const float*)ws)[WS_C2 + slot] * 512.0f;  // x
    const int b = patch >> 14;

    const int sz = (int)fmaxf(0.0f,   floorf(c0 - 2.0f));
    const int ez = (int)fminf(64.0f,  floorf(c0 + 2.0f));
    const int sy = (int)fmaxf(0.0f,   floorf(c1 - 8.0f));
    const int ey = (int)fminf(512.0f, floorf(c1 + 8.0f));
    const int sx = (int)fmaxf(0.0f,   floorf(c2 - 8.0f));
    const int ex = (int)fminf(512.0f, floorf(c2 + 8.0f));

    const int zz = lane >> 4;                 // 0..3
    const int yy = lane & 15;                 // 0..15
    const int zi = sz + zz;
    const int yi = sy + yy;
    const int ziC = min(zi, DVOL - 1);
    const int yiC = min(yi, HVOL - 1);
    const int a0  = sx & ~7;                  // 8B-aligned window base
    const int sh  = (sx & 7) * 8;

    const uint8_t* rp = seg8 + (size_t)b * DHW_ + ziC * HW_ + yiC * WVOL + a0;
    const uint64_t u0 = *(const uint64_t*)(rp);
    const uint64_t u1 = *(const uint64_t*)(rp + 8);
    const uint64_t u2 = *(const uint64_t*)(rp + 16);

    // 16 window bytes via funnel shift
    uint64_t A  = (u0 >> sh) | (sh ? (u1 << (64 - sh)) : 0ull);
    uint64_t Bv = (u1 >> sh) | (sh ? (u2 << (64 - sh)) : 0ull);

    // validity: x per byte, y/z whole-lane
    const int nv  = min(max(ex - sx, 0), 16);
    const int nvB = max(nv - 8, 0);
    uint64_t mA = (nv  >= 8) ? ~0ull : ((1ull << (8 * nv )) - 1ull);
    uint64_t mB = (nvB >= 8) ? ~0ull : ((1ull << (8 * nvB)) - 1ull);
    if (!((yi < ey) & (zi < ez))) { mA = 0ull; mB = 0ull; }
    A &= mA;  Bv &= mB;

    // --- packed 8-bit histogram: cc[k] holds regions 4k..4k+3 --------------
    unsigned cc[5] = {0u, 0u, 0u, 0u, 0u};
    const uint32_t w0 = (uint32_t)A,  w1 = (uint32_t)(A  >> 32);
    const uint32_t w2 = (uint32_t)Bv, w3 = (uint32_t)(Bv >> 32);
    const uint32_t wd[4] = {w0, w1, w2, w3};
#pragma unroll
    for (int d = 0; d < 4; ++d) {
        const uint32_t x = wd[d];
#pragma unroll
        for (int j = 0; j < 4; ++j) {
            const int v = (int)((x >> (8 * j)) & 0xFFu);
            const int t = v - 1;                       // -1 if not counted
            const unsigned inc = 1u << ((t & 3) << 3);
            const int qk = t >> 2;                     // -1 matches no k
#pragma unroll
            for (int k = 0; k < 5; ++k)
                cc[k] += (qk == k) ? inc : 0u;
        }
    }

    // --- 3-step packed butterfly (8-lane groups; per-lane max 16 -> <=128) -
#pragma unroll
    for (int off = 1; off < 8; off <<= 1) {
#pragma unroll
        for (int k = 0; k < 5; ++k)
            cc[k] += (unsigned)__shfl_xor((int)cc[k], off);
    }

    // unpack 8-bit -> 2x16-bit, 3 more steps across the 8 groups
    unsigned lo[5], hi[5];
#pragma unroll
    for (int k = 0; k < 5; ++k) {
        lo[k] = cc[k] & 0x00FF00FFu;          // regions 4k (lo16), 4k+2 (hi16)
        hi[k] = (cc[k] >> 8) & 0x00FF00FFu;   // regions 4k+1,      4k+3
    }
#pragma unroll
    for (int off = 8; off < 64; off <<= 1) {
#pragma unroll
        for (int k = 0; k < 5; ++k) {
            lo[k] += (unsigned)__shfl_xor((int)lo[k], off);
            hi[k] += (unsigned)__shfl_xor((int)hi[k], off);
        }
    }

    unsigned S = 0u;
#pragma unroll
    for (int k = 0; k < 5; ++k) S += lo[k] + hi[k];
    const unsigned tot = (S & 0xFFFFu) + (S >> 16);   // <= 1024, no carry

    const int r = lane & 3;
    const unsigned sLo = (lane < 4) ? lo[0] : (lane < 8) ? lo[1]
                       : (lane < 12) ? lo[2] : (lane < 16) ? lo[3] : lo[4];
    const unsigned sHi = (lane < 4) ? hi[0] : (lane < 8) ? hi[1]
                       : (lane < 12) ? hi[2] : (lane < 16) ? hi[3] : hi[4];
    const unsigned fld = (r & 1) ? sHi : sLo;
    const unsigned cnt = (r & 2) ? (fld >> 16) : (fld & 0xFFFFu);

    if (lane < NREG) {
        const float nz = (float)max(ez - sz, 0);
        const float ny = (float)max(ey - sy, 0);
        const float nx = (float)max(ex - sx, 0);
        const float denom = fmaxf(nz * ny * nx, 1.0f);
        const float s = (float)tot / denom + (float)NREG * 1e-6f;
        const float a = (float)cnt / denom + 1e-6f;
        out[RF_N + patch * NREG + lane] = a / s;
    }
}

// ---------------------------------------------------------------------------
extern "C" void kernel_launch(void* const* d_in, const int* in_sizes, int n_in,
                              void* d_out, int out_size, void* d_ws, size_t ws_size,
                              hipStream_t stream)
{
    const int*   seg    = (const int*)d_in[0];
    const float* coords = (const float*)d_in[1];
    const float* proto  = (const float*)d_in[2];
    float*       out    = (float*)d_out;
    unsigned*    ws     = (unsigned*)d_ws;
    uint8_t*     seg8   = (uint8_t*)d_ws;

    hipLaunchKernelGGL(sort_kernel, dim3(TOTAL_PATCHES / CHUNK), dim3(1024),
                       0, stream, coords, ws);
    hipLaunchKernelGGL(compact_kernel, dim3(CMP_BLOCKS), dim3(CMP_THREADS),
                       0, stream, seg, proto, (uint32_t*)seg8, out);
    hipLaunchKernelGGL(assign_kernel, dim3(TOTAL_PATCHES / 4), dim3(256),
                       0, stream, seg8, ws, out);
}

// Round 10
// 55.323 us; speedup vs baseline: 1.2578x; 1.2578x over previous
//
#include <hip/hip_runtime.h>
#include <stdint.h>

#define NREG   20
#define EDIM   768
#define DVOL   64
#define HVOL   512
#define WVOL   512
#define HW_    (HVOL * WVOL)
#define DHW_   (DVOL * HVOL * WVOL)
#define NPATCH 16384
#define BTOT   2
#define PROTO_N (NREG * EDIM)            // 15360
#define RF_N    (BTOT * PROTO_N)         // 30720 floats (output 0)
#define TOTAL_PATCHES (BTOT * NPATCH)    // 32768
#define NBUCKET 1024                     // 2 b x 32 zbins x 16 ybins

// workspace layout (u32 words)
#define W_COUNTS 0                       // 1024 (zeroed by hipMemsetAsync)
#define W_OFFS   1024                    // 1024
#define W_KEYS   2048                    // 32768
#define W_PID    (W_KEYS + TOTAL_PATCHES)
#define W_C0     (W_PID  + TOTAL_PATCHES)
#define W_C1     (W_C0   + TOTAL_PATCHES)
#define W_C2     (W_C1   + TOTAL_PATCHES)

// 16-byte load with only 4-byte alignment guarantee.
struct __attribute__((packed, aligned(4))) int4p { int x, y, z, w; };

// ---------------------------------------------------------------------------
// Global counting sort, pass 1: keys + bucket counts (+ proto broadcast).
// ---------------------------------------------------------------------------
__global__ __launch_bounds__(256) void count_kernel(
    const float* __restrict__ coords,
    const float* __restrict__ proto,
    float*       __restrict__ out,
    unsigned*    __restrict__ ws)
{
    const int p = (int)blockIdx.x * 256 + (int)threadIdx.x;

    if (p < RF_N) out[p] = proto[p >= PROTO_N ? p - PROTO_N : p];

    const int b = p >> 14;
    const float zf = coords[p * 3 + 0] * 64.0f;
    const float yf = coords[p * 3 + 1] * 512.0f;
    const int zbin = ((int)zf) >> 1;              // 0..31
    const int ybin = ((int)yf) >> 5;              // 0..15
    const unsigned key = (unsigned)(b * 512 + zbin * 16 + ybin);
    ws[W_KEYS + p] = key;
    atomicAdd(&ws[W_COUNTS + key], 1u);
}

// ---------------------------------------------------------------------------
// Pass 2: exclusive prefix over 1024 buckets (one block).
// ---------------------------------------------------------------------------
__global__ __launch_bounds__(1024) void scan_kernel(unsigned* __restrict__ ws)
{
    __shared__ unsigned tmp[NBUCKET];
    const int t = threadIdx.x;
    const unsigned v = ws[W_COUNTS + t];
    tmp[t] = v;
    __syncthreads();
#pragma unroll
    for (int off = 1; off < NBUCKET; off <<= 1) {
        const unsigned y = (t >= off) ? tmp[t - off] : 0u;
        __syncthreads();
        tmp[t] += y;
        __syncthreads();
    }
    ws[W_OFFS + t] = tmp[t] - v;                  // exclusive prefix
}

// ---------------------------------------------------------------------------
// Pass 3: scatter pid + SoA coords into globally sorted order.
// ---------------------------------------------------------------------------
__global__ __launch_bounds__(256) void scatter_kernel(
    const float* __restrict__ coords, unsigned* __restrict__ ws)
{
    const int p = (int)blockIdx.x * 256 + (int)threadIdx.x;
    const unsigned key  = ws[W_KEYS + p];
    const unsigned rank = atomicAdd(&ws[W_OFFS + key], 1u);
    ws[W_PID + rank] = (unsigned)p;
    ((float*)ws)[W_C0 + rank] = coords[p * 3 + 0];
    ((float*)ws)[W_C1 + rank] = coords[p * 3 + 1];
    ((float*)ws)[W_C2 + rank] = coords[p * 3 + 2];
}

// ---------------------------------------------------------------------------
// Assign: one wave per globally-sorted slot. XCD swizzle gives XCD c the
// contiguous sorted range [c*4096, (c+1)*4096) -> each XCD's L2 only ever
// touches its ~1/8 spatial slice of the mask (sliding window, high reuse).
// Body = R6: 4 unconditional int4 gathers, packed 8-bit histogram, shfl
// butterfly reduce, fully in-register finish.
// ---------------------------------------------------------------------------
__global__ __launch_bounds__(256) void assign_kernel(
    const int*      __restrict__ seg,
    const unsigned* __restrict__ ws,
    float*          __restrict__ out)
{
    // 8192 blocks: bid&7 = XCD -> sorted quartile; bid>>3 = position within
    const int bid  = (int)blockIdx.x;
    const int sbid = (bid & 7) * 1024 + (bid >> 3);

    const int lane = threadIdx.x & 63;
    const int wave = threadIdx.x >> 6;
    const int slot = sbid * 4 + wave;

    const int   patch = (int)ws[W_PID + slot];                  // uniform
    const float c0 = ((const float*)ws)[W_C0 + slot] * 64.0f;   // z
    const float c1 = ((const float*)ws)[W_C1 + slot] * 512.0f;  // y
    const float c2 = ((const float*)ws)[W_C2 + slot] * 512.0f;  // x
    const int b = patch >> 14;

    const int sz = (int)fmaxf(0.0f,   floorf(c0 - 2.0f));
    const int ez = (int)fminf(64.0f,  floorf(c0 + 2.0f));
    const int sy = (int)fmaxf(0.0f,   floorf(c1 - 8.0f));
    const int ey = (int)fminf(512.0f, floorf(c1 + 8.0f));
    const int sx = (int)fmaxf(0.0f,   floorf(c2 - 8.0f));
    const int ex = (int)fminf(512.0f, floorf(c2 + 8.0f));

    const int xl4  = lane & 3;
    const int yy   = lane >> 2;
    const int p_lo = sx + 4 * xl4;
    const int st   = min(p_lo, WVOL - 4);
    const int yi   = sy + yy;
    const unsigned vy = (yi < ey) ? 0xFFFFFFFFu : 0u;
    const int yiC  = min(yi, HVOL - 1);
    const int rowbase = b * DHW_ + yiC * WVOL + st;

    unsigned vm[4];
#pragma unroll
    for (int j = 0; j < 4; ++j) {
        const int pos = st + j;
        vm[j] = (pos >= p_lo && pos < ex) ? vy : 0u;
    }

    // --- 4 unconditional gathers, issued back-to-back ----------------------
    int4p q0, q1, q2, q3;
    {
        const int z0 = min(sz + 0, DVOL - 1) * HW_;
        const int z1 = min(sz + 1, DVOL - 1) * HW_;
        const int z2 = min(sz + 2, DVOL - 1) * HW_;
        const int z3 = min(sz + 3, DVOL - 1) * HW_;
        q0 = *(const int4p*)(seg + rowbase + z0);
        q1 = *(const int4p*)(seg + rowbase + z1);
        q2 = *(const int4p*)(seg + rowbase + z2);
        q3 = *(const int4p*)(seg + rowbase + z3);
    }

    // --- packed 8-bit histogram: cc[k] holds regions 4k..4k+3 --------------
    unsigned cc[5] = {0u, 0u, 0u, 0u, 0u};
#pragma unroll
    for (int z = 0; z < 4; ++z) {
        const unsigned zm = (sz + z < ez) ? 0xFFFFFFFFu : 0u;
        const int4p qz = (z == 0) ? q0 : (z == 1) ? q1 : (z == 2) ? q2 : q3;
        const int vals[4] = {qz.x, qz.y, qz.z, qz.w};
#pragma unroll
        for (int j = 0; j < 4; ++j) {
            const int v = vals[j] & (int)(vm[j] & zm);   // invalid -> 0
            const int t = v - 1;                         // -1 if not counted
            const unsigned inc = 1u << ((t & 3) << 3);
            const int qk = t >> 2;                       // -1 matches no k
#pragma unroll
            for (int k = 0; k < 5; ++k)
                cc[k] += (qk == k) ? inc : 0u;
        }
    }

    // --- 3-step packed butterfly (8-lane groups; max 128/field) ------------
#pragma unroll
    for (int off = 1; off < 8; off <<= 1) {
#pragma unroll
        for (int k = 0; k < 5; ++k)
            cc[k] += (unsigned)__shfl_xor((int)cc[k], off);
    }

    // unpack 8-bit -> 2x16-bit, 3 more steps across the 8 groups
    unsigned lo[5], hi[5];
#pragma unroll
    for (int k = 0; k < 5; ++k) {
        lo[k] = cc[k] & 0x00FF00FFu;          // regions 4k (lo16), 4k+2 (hi16)
        hi[k] = (cc[k] >> 8) & 0x00FF00FFu;   // regions 4k+1,      4k+3
    }
#pragma unroll
    for (int off = 8; off < 64; off <<= 1) {
#pragma unroll
        for (int k = 0; k < 5; ++k) {
            lo[k] += (unsigned)__shfl_xor((int)lo[k], off);
            hi[k] += (unsigned)__shfl_xor((int)hi[k], off);
        }
    }

    unsigned S = 0u;
#pragma unroll
    for (int k = 0; k < 5; ++k) S += lo[k] + hi[k];
    const unsigned tot = (S & 0xFFFFu) + (S >> 16);   // <= 1024, no carry

    const int r = lane & 3;
    const unsigned sLo = (lane < 4) ? lo[0] : (lane < 8) ? lo[1]
                       : (lane < 12) ? lo[2] : (lane < 16) ? lo[3] : lo[4];
    const unsigned sHi = (lane < 4) ? hi[0] : (lane < 8) ? hi[1]
                       : (lane < 12) ? hi[2] : (lane < 16) ? hi[3] : hi[4];
    const unsigned fld = (r & 1) ? sHi : sLo;
    const unsigned cnt = (r & 2) ? (fld >> 16) : (fld & 0xFFFFu);

    if (lane < NREG) {
        const float nz = (float)max(ez - sz, 0);
        const float ny = (float)max(ey - sy, 0);
        const float nx = (float)max(ex - sx, 0);
        const float denom = fmaxf(nz * ny * nx, 1.0f);
        const float s = (float)tot / denom + (float)NREG * 1e-6f;
        const float a = (float)cnt / denom + 1e-6f;
        out[RF_N + patch * NREG + lane] = a / s;
    }
}

// ---------------------------------------------------------------------------
extern "C" void kernel_launch(void* const* d_in, const int* in_sizes, int n_in,
                              void* d_out, int out_size, void* d_ws, size_t ws_size,
                              hipStream_t stream)
{
    const int*   seg    = (const int*)d_in[0];
    const float* coords = (const float*)d_in[1];
    const float* proto  = (const float*)d_in[2];
    float*       out    = (float*)d_out;
    unsigned*    ws     = (unsigned*)d_ws;

    hipMemsetAsync(ws, 0, NBUCKET * sizeof(unsigned), stream);
    hipLaunchKernelGGL(count_kernel, dim3(TOTAL_PATCHES / 256), dim3(256),
                       0, stream, coords, proto, out, ws);
    hipLaunchKernelGGL(scan_kernel, dim3(1), dim3(NBUCKET), 0, stream, ws);
    hipLaunchKernelGGL(scatter_kernel, dim3(TOTAL_PATCHES / 256), dim3(256),
                       0, stream, coords, ws);
    hipLaunchKernelGGL(assign_kernel, dim3(TOTAL_PATCHES / 4), dim3(256),
                       0, stream, seg, ws, out);
}